// Round 17
// baseline (3007.384 us; speedup 1.0000x reference)
//
#include <hip/hip_runtime.h>
#include <hip/hip_bf16.h>

constexpr int NG   = 8;          // graphs
constexpr int NPG  = 4096;       // nodes per graph
constexpr int NT   = NG * NPG;   // 32768 total nodes
constexpr int NS   = 2048;       // fps samples per graph
constexpr int GS   = NG * NS;    // 16384
constexpr int KN   = 64;         // max neighbors
constexpr int NE   = NG * 65536; // 524288 edges
constexpr int NC   = 13;         // classes
constexpr int NWORK = 248;       // worker blocks in phaseA (blocks 8..255)
constexpr int NSTR = 64;         // worker blocks that stream radius+pointconv
constexpr int SPB  = 16;         // samples per block in post2 feat3
constexpr int NF3B = GS / SPB;   // 1024 feat3 blocks

__device__ __forceinline__ float inp_val(const float* norm, const float* pos, const float* x,
                                         int node, int dim) {
  if (dim < 3) return norm[(size_t)node * 3 + dim];
  if (dim < 6) return pos[(size_t)node * 3 + (dim - 3)];
  return x[(size_t)node * 2 + (dim - 6)];
}

// agent-scope arrive-and-wait barrier among the NWORK worker blocks
__device__ __forceinline__ void wbar(int* ctrs, int k, int target) {
  __syncthreads();
  __threadfence();
  if (threadIdx.x == 0) {
    __hip_atomic_fetch_add(&ctrs[k], 1, __ATOMIC_RELEASE, __HIP_MEMORY_SCOPE_AGENT);
    while (__hip_atomic_load(&ctrs[k], __ATOMIC_ACQUIRE, __HIP_MEMORY_SCOPE_AGENT) < target)
      __builtin_amdgcn_s_sleep(16);
  }
  __syncthreads();
}

// ---- phase A (cooperative, 256 blocks x 256 thr) ----
// blocks 0-7: fps; flushes qpos/idxf every 64 steps, publishes progress at
//   wctr[32+g*32] (128B-padded -> no cross-graph cacheline contention).
// blocks 8-255: feat1+deg1 -> scan -> fill1 -> agg1+feat2 -> agg2;
//   then blocks 8..71 stream {radius+mapset+pointconv} chunks under fps; rest exit.
__global__ __launch_bounds__(256, 1) void phaseA_kernel(
    const float* __restrict__ pos, int* __restrict__ idxf, float* __restrict__ qpos,
    const float* __restrict__ norm, const float* __restrict__ x,
    const float* __restrict__ W1, float* __restrict__ t1,
    const int* __restrict__ ei, int* __restrict__ deg,
    int* __restrict__ off1, int* __restrict__ cur1, int* __restrict__ el1,
    const float* __restrict__ b1, const float* __restrict__ W2, float* __restrict__ t2,
    const float* __restrict__ b2, float* __restrict__ h2,
    int* __restrict__ mapv, int* __restrict__ cols, int* __restrict__ cnt,
    float* __restrict__ xint, int* __restrict__ wctr) {
  if (blockIdx.x >= 8) {
    // ================= workers =================
    const int wb = blockIdx.x - 8;
    const int sub = threadIdx.x >> 6;
    const int f = threadIdx.x & 63;
    __shared__ float wrow[4][80];
    __shared__ int sscan[256];
    __shared__ float spx[NPG], spy[NPG], spz[NPG];  // stage-5 position cache
    __shared__ int scnt[256];
    __shared__ int schunk;
    for (int n0 = wb * 4; n0 < NT; n0 += NWORK * 4) {
      int n = n0 + sub;
      if (f < 8) wrow[sub][f] = inp_val(norm, pos, x, n, f);
      float acc = 0.f;  // same-wave LDS write->read, lockstep
#pragma unroll
      for (int i = 0; i < 8; ++i) acc += wrow[sub][i] * W1[i * 64 + f];
      t1[(size_t)n * 64 + f] = acc;
    }
    for (int e = wb * 256 + threadIdx.x; e < NE; e += NWORK * 256)
      atomicAdd(&deg[ei[NE + e]], 1);
    wbar(wctr, 0, NWORK);
    if (wb == 0) {
      int t = threadIdx.x, base = t * 128, s = 0;
      for (int i = 0; i < 128; ++i) s += deg[base + i];
      sscan[t] = s;
      __syncthreads();
      for (int d = 1; d < 256; d <<= 1) {
        int v = (t >= d) ? sscan[t - d] : 0;
        __syncthreads();
        sscan[t] += v;
        __syncthreads();
      }
      int excl = (t == 0) ? 0 : sscan[t - 1];
      for (int i = 0; i < 128; ++i) { off1[base + i] = excl; excl += deg[base + i]; }
      if (t == 255) off1[NT] = sscan[255];
    }
    wbar(wctr, 1, NWORK);
    for (int e = wb * 256 + threadIdx.x; e < NE; e += NWORK * 256) {
      int sN = ei[e], dN = ei[NE + e];
      int p = off1[dN] + atomicAdd(&cur1[dN], 1);
      el1[p] = sN;
    }
    wbar(wctr, 2, NWORK);
    for (int n0 = wb * 4; n0 < NT; n0 += NWORK * 4) {
      int n = n0 + sub;
      int e0 = off1[n], e1 = off1[n + 1];
      float acc = 0.f;
      for (int j = e0; j < e1; ++j) acc += t1[(size_t)el1[j] * 64 + f];
      wrow[sub][f] = fmaxf(acc + b1[f], 0.f);
      if (f < 8) wrow[sub][64 + f] = inp_val(norm, pos, x, n, f);
      float a0 = 0.f, a1 = 0.f;
#pragma unroll 8
      for (int i = 0; i < 72; ++i) {
        float r = wrow[sub][i];
        a0 += r * W2[i * 128 + f];
        a1 += r * W2[i * 128 + 64 + f];
      }
      t2[(size_t)n * 128 + f] = a0;
      t2[(size_t)n * 128 + 64 + f] = a1;
    }
    wbar(wctr, 3, NWORK);
    {
      const int f2 = threadIdx.x & 127, sub2 = threadIdx.x >> 7;
      for (int n0 = wb * 2; n0 < NT; n0 += NWORK * 2) {
        int n = n0 + sub2;
        int e0 = off1[n], e1 = off1[n + 1];
        float acc = 0.f;
        for (int j = e0; j < e1; ++j) acc += t2[(size_t)el1[j] * 128 + f2];
        h2[(size_t)n * 128 + f2] = fmaxf(acc + b2[f2], 0.f);
      }
    }
    if (wb >= NSTR) return;  // most of the chip goes quiet for fps
    // stage 5: streamed radius + mapset + pointconv (r10-proven exact arithmetic)
    for (;;) {
      if (threadIdx.x == 0)
        schunk = __hip_atomic_fetch_add(&wctr[8], 1, __ATOMIC_RELAXED,
                                        __HIP_MEMORY_SCOPE_AGENT);
      __syncthreads();
      int chunk = schunk;
      __syncthreads();
      if (chunk >= 64) break;
      int gC = chunk >> 3, c0 = (chunk & 7) * 256;
      const float* pgc = pos + (size_t)gC * NPG * 3;
      for (int i = threadIdx.x; i < NPG * 3; i += 256) {
        float v = pgc[i]; int node = i / 3, cc = i - node * 3;
        if (cc == 0) spx[node] = v; else if (cc == 1) spy[node] = v; else spz[node] = v;
      }
      if (threadIdx.x == 0) {  // wait for fps to publish these samples
        while (__hip_atomic_load(&wctr[32 + gC * 32], __ATOMIC_ACQUIRE,
                                 __HIP_MEMORY_SCOPE_AGENT) < c0 + 256)
          __builtin_amdgcn_s_sleep(64);
      }
      __syncthreads();
      // radius (exact fp32, first-K lowest index) + mapset; 1 thread/sample
      {
        int m = gC * NS + c0 + threadIdx.x;
        mapv[idxf[m]] = m;
        float qx = qpos[(size_t)m * 3], qy = qpos[(size_t)m * 3 + 1],
              qz = qpos[(size_t)m * 3 + 2];
        int* out = cols + (size_t)m * KN;
        int c = 0;
        for (int i = 0; i < NPG; ++i) {
          float dx = __fsub_rn(spx[i], qx);
          float dy = __fsub_rn(spy[i], qy);
          float dz = __fsub_rn(spz[i], qz);
          float d2 = __fadd_rn(__fadd_rn(__fmul_rn(dx, dx), __fmul_rn(dy, dy)),
                               __fmul_rn(dz, dz));
          if (d2 < 0.16f) {
            out[c++] = i;
            if (c == KN) break;
          }
        }
        scnt[threadIdx.x] = c;
        cnt[m] = c;
      }
      __syncthreads();
      // pointconv: 4 samples concurrently (64 feature lanes each)
      for (int ss = (threadIdx.x >> 6); ss < 256; ss += 4) {
        int fc = threadIdx.x & 63;
        int m = gC * NS + c0 + ss;
        int n = scnt[ss];
        const int* cl = cols + (size_t)m * KN;
        float m0 = -INFINITY, m1 = -INFINITY, mpv = -INFINITY;
        for (int k = 0; k < n; ++k) {
          int cc = cl[k];
          size_t b = (size_t)(gC * NPG + cc);
          m0 = fmaxf(m0, h2[b * 128 + fc]);
          m1 = fmaxf(m1, h2[b * 128 + 64 + fc]);
          if (fc < 3) mpv = fmaxf(mpv, (fc == 0 ? spx[cc] : (fc == 1 ? spy[cc] : spz[cc])));
        }
        float* xo = xint + (size_t)m * 131;
        xo[fc] = m0;
        xo[64 + fc] = m1;
        if (fc < 3) xo[128 + fc] = __fsub_rn(mpv, qpos[(size_t)m * 3 + fc]);
      }
      __syncthreads();  // before next chunk restages spx
    }
    return;
  }
  // ================= FPS (r14 arithmetic; batched flush + padded progress) ==========
  const int g = blockIdx.x;
  __shared__ float4 sq[2][4];
  __shared__ int sidx[2][4];
  __shared__ float4 qrec[NS];
  __shared__ int irec[NS];
  const float* pg = pos + (size_t)g * NPG * 3;
  const int tid = threadIdx.x;
  const int wave = tid >> 6, lane = tid & 63;
  const int p0 = tid * 16;

  float a[48];
  {
    const float4* pg4 = reinterpret_cast<const float4*>(pg + (size_t)p0 * 3);
#pragma unroll
    for (int j = 0; j < 12; ++j) {
      float4 t = pg4[j];
      a[4 * j + 0] = t.x; a[4 * j + 1] = t.y; a[4 * j + 2] = t.z; a[4 * j + 3] = t.w;
    }
  }
  float px[16], py[16], pz[16], mind[16];
#pragma unroll
  for (int i = 0; i < 16; ++i) {
    px[i] = a[3 * i]; py[i] = a[3 * i + 1]; pz[i] = a[3 * i + 2];
    mind[i] = __int_as_float(0x7f800000);
  }
  float cx = pg[0], cy = pg[1], cz = pg[2];
  int idx_sel = 0;

  for (int s = 0; s < NS; ++s) {
    if (tid == 0) { irec[s] = idx_sel; qrec[s] = make_float4(cx, cy, cz, 0.f); }
    float bestv = -1.f, bx = 0.f, by = 0.f, bz = 0.f;
    int bi = 0;
#pragma unroll
    for (int i = 0; i < 16; ++i) {
      float dx = __fsub_rn(px[i], cx);
      float dy = __fsub_rn(py[i], cy);
      float dz = __fsub_rn(pz[i], cz);
      float dd = __fadd_rn(__fadd_rn(__fmul_rn(dx, dx), __fmul_rn(dy, dy)), __fmul_rn(dz, dz));
      float nm = fminf(mind[i], dd);
      mind[i] = nm;
      bool gt = nm > bestv;   // strict > keeps first occurrence
      bestv = gt ? nm : bestv;
      bx = gt ? px[i] : bx;
      by = gt ? py[i] : by;
      bz = gt ? pz[i] : bz;
      bi = gt ? i : bi;
    }
    float v = bestv;
    v = fmaxf(v, __int_as_float(__builtin_amdgcn_update_dpp(0, __float_as_int(v), 0x111, 0xF, 0xF, true)));
    v = fmaxf(v, __int_as_float(__builtin_amdgcn_update_dpp(0, __float_as_int(v), 0x112, 0xF, 0xF, true)));
    v = fmaxf(v, __int_as_float(__builtin_amdgcn_update_dpp(0, __float_as_int(v), 0x114, 0xF, 0xF, true)));
    v = fmaxf(v, __int_as_float(__builtin_amdgcn_update_dpp(0, __float_as_int(v), 0x118, 0xF, 0xF, true)));
    v = fmaxf(v, __int_as_float(__builtin_amdgcn_update_dpp(0, __float_as_int(v), 0x142, 0xF, 0xF, true)));
    v = fmaxf(v, __int_as_float(__builtin_amdgcn_update_dpp(0, __float_as_int(v), 0x143, 0xF, 0xF, true)));
    int maxbits = __builtin_amdgcn_readlane(__float_as_int(v), 63);
    float wavemax = __int_as_float(maxbits);
    unsigned long long ball = __ballot(bestv == wavemax);
    int winner = __ffsll(ball) - 1;  // lowest lane = lowest index (contiguous ownership)
    int b = s & 1;
    if (lane == winner) {
      sq[b][wave] = make_float4(bx, by, bz, wavemax);
      sidx[b][wave] = p0 + bi;
    }
    __syncthreads();
    float4 q0 = sq[b][0], q1 = sq[b][1], q2 = sq[b][2], q3 = sq[b][3];
    float4 qs = q3;
    if (q2.w >= qs.w) qs = q2;   // >= toward lower wave = lowest index on ties
    if (q1.w >= qs.w) qs = q1;
    if (q0.w >= qs.w) qs = q0;
    cx = qs.x; cy = qs.y; cz = qs.z;
    if (tid == 0) {
      int i0 = sidx[b][0], i1 = sidx[b][1], i2 = sidx[b][2], i3 = sidx[b][3];
      float r = q3.w; int is = i3;
      if (q2.w >= r) { r = q2.w; is = i2; }
      if (q1.w >= r) { r = q1.w; is = i1; }
      if (q0.w >= r) { r = q0.w; is = i0; }
      idx_sel = is;
    }
    // batched flush of the last 64 records + padded progress publish
    if ((s & 63) == 63) {
      int smp = (s - 63) + (tid >> 2);
      int comp = tid & 3;
      if (comp < 3) qpos[(size_t)(g * NS + smp) * 3 + comp] = ((float*)&qrec[smp])[comp];
      else idxf[g * NS + smp] = g * NPG + irec[smp];
      __threadfence();
      __syncthreads();
      if (tid == 0)
        __hip_atomic_store(&wctr[32 + g * 32], s + 1, __ATOMIC_RELEASE,
                           __HIP_MEMORY_SCOPE_AGENT);
    }
  }
}

// ---- post2: feat3 (SPB samples/block) + deg2 (XCD-pinned edge blocks) ----
__global__ void post2_kernel(const float* __restrict__ xint, const int* __restrict__ idxf,
                             const float* __restrict__ norm, const float* __restrict__ pos,
                             const float* __restrict__ x, const float* __restrict__ W3,
                             float* __restrict__ t3,
                             const int* __restrict__ ei, const int* __restrict__ mp,
                             int* __restrict__ deg) {
  if (blockIdx.x >= NF3B) {
    int wb = blockIdx.x - NF3B;
    int eb = (wb & 7) * 256 + (wb >> 3);
    int e = eb * 256 + threadIdx.x;
    int ns = mp[ei[e]], nd = mp[ei[NE + e]];
    if (ns >= 0 && nd >= 0) atomicAdd(&deg[nd], 1);
    return;
  }
  __shared__ float srow[SPB][140];
  const int m0 = blockIdx.x * SPB;
  for (int jj = threadIdx.x; jj < SPB * 139; jj += 256) {
    int sub = jj / 139, i = jj - sub * 139;
    int m = m0 + sub;
    srow[sub][i] = (i < 131) ? xint[(size_t)m * 131 + i]
                             : inp_val(norm, pos, x, idxf[m], i - 131);
  }
  __syncthreads();
  int f = threadIdx.x;
  float acc[SPB];
#pragma unroll
  for (int s = 0; s < SPB; ++s) acc[s] = 0.f;
#pragma unroll 4
  for (int i = 0; i < 139; ++i) {
    float wv = W3[i * 256 + f];
#pragma unroll
    for (int s = 0; s < SPB; ++s) acc[s] += srow[s][i] * wv;
  }
#pragma unroll
  for (int s = 0; s < SPB; ++s) t3[(size_t)(m0 + s) * 256 + f] = acc[s];
}

__global__ void fill2_kernel(const int* __restrict__ ei, const int* __restrict__ mp,
                             const int* __restrict__ off, int* __restrict__ cur,
                             int* __restrict__ el) {
  int b = blockIdx.x;
  int eb = (b & 7) * 256 + (b >> 3);
  int e = eb * 256 + threadIdx.x;
  int ns = mp[ei[e]], nd = mp[ei[NE + e]];
  if (ns >= 0 && nd >= 0) {
    int p = off[nd] + atomicAdd(&cur[nd], 1);
    el[p] = ns;
  }
}

// single-block exclusive scan, n <= 32768, writes out[0..n]
__global__ __launch_bounds__(1024) void scan_kernel(const int* __restrict__ in,
                                                    int* __restrict__ out, int n) {
  __shared__ int ls[1024];
  int tid = threadIdx.x;
  int per = (n + 1023) >> 10;
  int base = tid * per;
  int s = 0;
  for (int i = 0; i < per; ++i) { int idx = base + i; if (idx < n) s += in[idx]; }
  ls[tid] = s;
  __syncthreads();
  for (int d = 1; d < 1024; d <<= 1) {
    int v = (tid >= d) ? ls[tid - d] : 0;
    __syncthreads();
    ls[tid] += v;
    __syncthreads();
  }
  int excl = (tid == 0) ? 0 : ls[tid - 1];
  for (int i = 0; i < per; ++i) {
    int idx = base + i;
    if (idx < n) { out[idx] = excl; excl += in[idx]; }
  }
  if (tid == 1023) out[n] = ls[1023];
}

// ---- agg3 + pool fused, XCD-pinned so t3[graph] (2MB) is L2-local ----
__global__ void aggpool_kernel(const float* __restrict__ t, const int* __restrict__ off,
                               const int* __restrict__ el, const float* __restrict__ b,
                               float* __restrict__ pooled) {
  int node = (blockIdx.x & 7) * 2048 + (blockIdx.x >> 3);
  int f = threadIdx.x;
  int e0 = off[node], e1 = off[node + 1];
  float acc = 0.f;
  for (int j = e0; j < e1; ++j) acc += t[(size_t)el[j] * 256 + f];
  float val = fmaxf(acc + b[f], 0.f);
  atomicMax((int*)pooled + (node >> 11) * 256 + f, __float_as_int(val));
}

__global__ void head_kernel(const float* __restrict__ pooled, const float* __restrict__ lw,
                            const float* __restrict__ lb, float* __restrict__ outp) {
  __shared__ float lg[NG * NC];
  int t = threadIdx.x;
  if (t < NG * NC) {
    int g = t / NC, c = t % NC;
    float acc = lb[c];
    for (int k = 0; k < 256; ++k) acc += pooled[g * 256 + k] * lw[k * NC + c];
    lg[t] = acc;
  }
  __syncthreads();
  if (t < NG) {
    int g = t;
    float mx = -INFINITY;
    for (int c = 0; c < NC; ++c) mx = fmaxf(mx, lg[g * NC + c]);
    float sum = 0.f;
    for (int c = 0; c < NC; ++c) sum += expf(lg[g * NC + c] - mx);
    float lse = logf(sum);
    float ov[NC];
    float mx2 = -INFINITY;
    for (int c = 0; c < NC; ++c) {
      ov[c] = lg[g * NC + c] - mx - lse;
      outp[g * NC + c] = ov[c];
      mx2 = fmaxf(mx2, ov[c]);
    }
    float s2 = 0.f;
    for (int c = 0; c < NC; ++c) s2 += expf(ov[c] - mx2);
    for (int c = 0; c < NC; ++c) outp[NG * NC + g * NC + c] = expf(ov[c] - mx2) / s2;
  }
}

extern "C" void kernel_launch(void* const* d_in, const int* in_sizes, int n_in,
                              void* d_out, int out_size, void* d_ws, size_t ws_size,
                              hipStream_t stream) {
  const float* norm = (const float*)d_in[0];
  const float* pos  = (const float*)d_in[1];
  const float* x    = (const float*)d_in[2];
  const int* ei     = (const int*)d_in[3];   // int32! row0 = src, row1 = dst
  const float* W1 = (const float*)d_in[5];
  const float* b1 = (const float*)d_in[6];
  const float* W2 = (const float*)d_in[7];
  const float* b2 = (const float*)d_in[8];
  const float* W3 = (const float*)d_in[9];
  const float* b3 = (const float*)d_in[10];
  const float* lw = (const float*)d_in[11];
  const float* lb = (const float*)d_in[12];
  float* outp = (float*)d_out;

  char* w = (char*)d_ws;
  size_t o = 0;
  auto alloc = [&](size_t bytes) -> void* {
    void* p = w + o;
    o = (o + bytes + 255) & ~(size_t)255;
    return p;
  };
  // zero-group (single memset): deg1,cur1,deg2,cur2,pooled,wctr contiguous
  int* deg1   = (int*)alloc((size_t)NT * 4);
  int* cur1   = (int*)alloc((size_t)NT * 4);
  int* deg2   = (int*)alloc((size_t)GS * 4);
  int* cur2   = (int*)alloc((size_t)GS * 4);
  float* pooled = (float*)alloc((size_t)NG * 256 * 4);
  int* wctr   = (int*)alloc(2048);   // padded progress counters at [32+g*32]
  size_t zlen = o;
  float* A    = (float*)alloc((size_t)NT * 128 * 4);  // t2 -> t3
  float* Bf   = (float*)alloc((size_t)NT * 128 * 4);  // h2
  float* T1   = (float*)alloc((size_t)NT * 64 * 4);   // t1
  float* xint = (float*)alloc((size_t)GS * 131 * 4);
  int* cols   = (int*)alloc((size_t)GS * KN * 4);
  int* cnt    = (int*)alloc((size_t)GS * 4);
  int* off1   = (int*)alloc((size_t)(NT + 1) * 4);
  int* el1    = (int*)alloc((size_t)NE * 4);
  int* off2   = (int*)alloc((size_t)(GS + 1) * 4);
  int* el2    = (int*)alloc((size_t)NE * 4);
  int* idxf   = (int*)alloc((size_t)GS * 4);
  float* qpos = (float*)alloc((size_t)GS * 3 * 4);
  int* mapv   = (int*)alloc((size_t)NT * 4);

  hipMemsetAsync(w, 0, zlen, stream);
  hipMemsetAsync(mapv, 0xFF, (size_t)NT * 4, stream);  // -1

  // phase A (cooperative): fps ∥ {GCN layers 1-2, then streamed radius+pointconv}
  {
    void* ka[] = {(void*)&pos, (void*)&idxf, (void*)&qpos, (void*)&norm, (void*)&x,
                  (void*)&W1, (void*)&T1, (void*)&ei, (void*)&deg1,
                  (void*)&off1, (void*)&cur1, (void*)&el1,
                  (void*)&b1, (void*)&W2, (void*)&A, (void*)&b2, (void*)&Bf,
                  (void*)&mapv, (void*)&cols, (void*)&cnt, (void*)&xint,
                  (void*)&wctr};
    hipLaunchCooperativeKernel((const void*)phaseA_kernel, dim3(8 + NWORK), dim3(256),
                               ka, 0, stream);
  }
  // tail (radius/pointconv absorbed into phase A)
  post2_kernel<<<NF3B + 2048, 256, 0, stream>>>(xint, idxf, norm, pos, x, W3, A,
                                                ei, mapv, deg2);
  scan_kernel<<<1, 1024, 0, stream>>>(deg2, off2, GS);
  fill2_kernel<<<2048, 256, 0, stream>>>(ei, mapv, off2, cur2, el2);
  aggpool_kernel<<<GS, 256, 0, stream>>>(A, off2, el2, b3, pooled);
  head_kernel<<<1, 128, 0, stream>>>(pooled, lw, lb, outp);
}

// Round 18
// 1986.421 us; speedup vs baseline: 1.5140x; 1.5140x over previous
//
#include <hip/hip_runtime.h>
#include <hip/hip_bf16.h>

constexpr int NG   = 8;          // graphs
constexpr int NPG  = 4096;       // nodes per graph
constexpr int NT   = NG * NPG;   // 32768 total nodes
constexpr int NS   = 2048;       // fps samples per graph
constexpr int GS   = NG * NS;    // 16384
constexpr int KN   = 64;         // max neighbors
constexpr int NE   = NG * 65536; // 524288 edges
constexpr int NC   = 13;         // classes
constexpr int NWORK = 248;       // worker blocks in phaseA (blocks 8..255)
constexpr int SPB  = 16;         // samples per block in post2 feat3
constexpr int NF3B = GS / SPB;   // 1024 feat3 blocks

__device__ __forceinline__ float inp_val(const float* norm, const float* pos, const float* x,
                                         int node, int dim) {
  if (dim < 3) return norm[(size_t)node * 3 + dim];
  if (dim < 6) return pos[(size_t)node * 3 + (dim - 3)];
  return x[(size_t)node * 2 + (dim - 6)];
}

// agent-scope arrive-and-wait barrier among the NWORK worker blocks
__device__ __forceinline__ void wbar(int* ctrs, int k, int target) {
  __syncthreads();
  __threadfence();
  if (threadIdx.x == 0) {
    __hip_atomic_fetch_add(&ctrs[k], 1, __ATOMIC_RELEASE, __HIP_MEMORY_SCOPE_AGENT);
    while (__hip_atomic_load(&ctrs[k], __ATOMIC_ACQUIRE, __HIP_MEMORY_SCOPE_AGENT) < target)
      __builtin_amdgcn_s_sleep(16);
  }
  __syncthreads();
}

// ---- phase A (cooperative, 256 blocks x 256 thr) — r14/r16 measured-best form ----
// blocks 0-7: fps (single graph each, 16 pts/thread, DPP reduce, one barrier/step).
// blocks 8-255: feat1+deg1 -> scan -> fill1 -> agg1+feat2 -> agg2, then exit.
__global__ __launch_bounds__(256, 1) void phaseA_kernel(
    const float* __restrict__ pos, int* __restrict__ idxf, float* __restrict__ qpos,
    const float* __restrict__ norm, const float* __restrict__ x,
    const float* __restrict__ W1, float* __restrict__ t1,
    const int* __restrict__ ei, int* __restrict__ deg,
    int* __restrict__ off1, int* __restrict__ cur1, int* __restrict__ el1,
    const float* __restrict__ b1, const float* __restrict__ W2, float* __restrict__ t2,
    const float* __restrict__ b2, float* __restrict__ h2,
    int* __restrict__ wctr) {
  if (blockIdx.x >= 8) {
    const int wb = blockIdx.x - 8;
    const int sub = threadIdx.x >> 6;
    const int f = threadIdx.x & 63;
    __shared__ float wrow[4][80];
    __shared__ int sscan[256];
    for (int n0 = wb * 4; n0 < NT; n0 += NWORK * 4) {
      int n = n0 + sub;
      if (f < 8) wrow[sub][f] = inp_val(norm, pos, x, n, f);
      float acc = 0.f;
#pragma unroll
      for (int i = 0; i < 8; ++i) acc += wrow[sub][i] * W1[i * 64 + f];
      t1[(size_t)n * 64 + f] = acc;
    }
    for (int e = wb * 256 + threadIdx.x; e < NE; e += NWORK * 256)
      atomicAdd(&deg[ei[NE + e]], 1);
    wbar(wctr, 0, NWORK);
    if (wb == 0) {
      int t = threadIdx.x, base = t * 128, s = 0;
      for (int i = 0; i < 128; ++i) s += deg[base + i];
      sscan[t] = s;
      __syncthreads();
      for (int d = 1; d < 256; d <<= 1) {
        int v = (t >= d) ? sscan[t - d] : 0;
        __syncthreads();
        sscan[t] += v;
        __syncthreads();
      }
      int excl = (t == 0) ? 0 : sscan[t - 1];
      for (int i = 0; i < 128; ++i) { off1[base + i] = excl; excl += deg[base + i]; }
      if (t == 255) off1[NT] = sscan[255];
    }
    wbar(wctr, 1, NWORK);
    for (int e = wb * 256 + threadIdx.x; e < NE; e += NWORK * 256) {
      int sN = ei[e], dN = ei[NE + e];
      int p = off1[dN] + atomicAdd(&cur1[dN], 1);
      el1[p] = sN;
    }
    wbar(wctr, 2, NWORK);
    for (int n0 = wb * 4; n0 < NT; n0 += NWORK * 4) {
      int n = n0 + sub;
      int e0 = off1[n], e1 = off1[n + 1];
      float acc = 0.f;
      for (int j = e0; j < e1; ++j) acc += t1[(size_t)el1[j] * 64 + f];
      wrow[sub][f] = fmaxf(acc + b1[f], 0.f);
      if (f < 8) wrow[sub][64 + f] = inp_val(norm, pos, x, n, f);
      float a0 = 0.f, a1 = 0.f;
#pragma unroll 8
      for (int i = 0; i < 72; ++i) {
        float r = wrow[sub][i];
        a0 += r * W2[i * 128 + f];
        a1 += r * W2[i * 128 + 64 + f];
      }
      t2[(size_t)n * 128 + f] = a0;
      t2[(size_t)n * 128 + 64 + f] = a1;
    }
    wbar(wctr, 3, NWORK);
    {
      const int f2 = threadIdx.x & 127, sub2 = threadIdx.x >> 7;
      for (int n0 = wb * 2; n0 < NT; n0 += NWORK * 2) {
        int n = n0 + sub2;
        int e0 = off1[n], e1 = off1[n + 1];
        float acc = 0.f;
        for (int j = e0; j < e1; ++j) acc += t2[(size_t)el1[j] * 128 + f2];
        h2[(size_t)n * 128 + f2] = fmaxf(acc + b2[f2], 0.f);
      }
    }
    return;
  }
  // ================= FPS (r7/r9/r14 arithmetic, bulk write at end) =================
  const int g = blockIdx.x;
  __shared__ float4 sq[2][4];
  __shared__ int sidx[2][4];
  __shared__ float4 qrec[NS];
  __shared__ int irec[NS];
  const float* pg = pos + (size_t)g * NPG * 3;
  const int tid = threadIdx.x;
  const int wave = tid >> 6, lane = tid & 63;
  const int p0 = tid * 16;

  float a[48];
  {
    const float4* pg4 = reinterpret_cast<const float4*>(pg + (size_t)p0 * 3);
#pragma unroll
    for (int j = 0; j < 12; ++j) {
      float4 t = pg4[j];
      a[4 * j + 0] = t.x; a[4 * j + 1] = t.y; a[4 * j + 2] = t.z; a[4 * j + 3] = t.w;
    }
  }
  float px[16], py[16], pz[16], mind[16];
#pragma unroll
  for (int i = 0; i < 16; ++i) {
    px[i] = a[3 * i]; py[i] = a[3 * i + 1]; pz[i] = a[3 * i + 2];
    mind[i] = __int_as_float(0x7f800000);
  }
  float cx = pg[0], cy = pg[1], cz = pg[2];
  int idx_sel = 0;

  for (int s = 0; s < NS; ++s) {
    if (tid == 0) { irec[s] = idx_sel; qrec[s] = make_float4(cx, cy, cz, 0.f); }
    float bestv = -1.f, bx = 0.f, by = 0.f, bz = 0.f;
    int bi = 0;
#pragma unroll
    for (int i = 0; i < 16; ++i) {
      float dx = __fsub_rn(px[i], cx);
      float dy = __fsub_rn(py[i], cy);
      float dz = __fsub_rn(pz[i], cz);
      float dd = __fadd_rn(__fadd_rn(__fmul_rn(dx, dx), __fmul_rn(dy, dy)), __fmul_rn(dz, dz));
      float nm = fminf(mind[i], dd);
      mind[i] = nm;
      bool gt = nm > bestv;   // strict > keeps first occurrence
      bestv = gt ? nm : bestv;
      bx = gt ? px[i] : bx;
      by = gt ? py[i] : by;
      bz = gt ? pz[i] : bz;
      bi = gt ? i : bi;
    }
    float v = bestv;
    v = fmaxf(v, __int_as_float(__builtin_amdgcn_update_dpp(0, __float_as_int(v), 0x111, 0xF, 0xF, true)));
    v = fmaxf(v, __int_as_float(__builtin_amdgcn_update_dpp(0, __float_as_int(v), 0x112, 0xF, 0xF, true)));
    v = fmaxf(v, __int_as_float(__builtin_amdgcn_update_dpp(0, __float_as_int(v), 0x114, 0xF, 0xF, true)));
    v = fmaxf(v, __int_as_float(__builtin_amdgcn_update_dpp(0, __float_as_int(v), 0x118, 0xF, 0xF, true)));
    v = fmaxf(v, __int_as_float(__builtin_amdgcn_update_dpp(0, __float_as_int(v), 0x142, 0xF, 0xF, true)));
    v = fmaxf(v, __int_as_float(__builtin_amdgcn_update_dpp(0, __float_as_int(v), 0x143, 0xF, 0xF, true)));
    int maxbits = __builtin_amdgcn_readlane(__float_as_int(v), 63);
    float wavemax = __int_as_float(maxbits);
    unsigned long long ball = __ballot(bestv == wavemax);
    int winner = __ffsll(ball) - 1;  // lowest lane = lowest index (contiguous ownership)
    int b = s & 1;
    if (lane == winner) {
      sq[b][wave] = make_float4(bx, by, bz, wavemax);
      sidx[b][wave] = p0 + bi;
    }
    __syncthreads();
    float4 q0 = sq[b][0], q1 = sq[b][1], q2 = sq[b][2], q3 = sq[b][3];
    float4 qs = q3;
    if (q2.w >= qs.w) qs = q2;   // >= toward lower wave = lowest index on ties
    if (q1.w >= qs.w) qs = q1;
    if (q0.w >= qs.w) qs = q0;
    cx = qs.x; cy = qs.y; cz = qs.z;
    if (tid == 0) {
      int i0 = sidx[b][0], i1 = sidx[b][1], i2 = sidx[b][2], i3 = sidx[b][3];
      float r = q3.w; int is = i3;
      if (q2.w >= r) { r = q2.w; is = i2; }
      if (q1.w >= r) { r = q1.w; is = i1; }
      if (q0.w >= r) { r = q0.w; is = i0; }
      idx_sel = is;
    }
  }
  __syncthreads();
  for (int j = tid; j < NS; j += 256) {
    idxf[g * NS + j] = g * NPG + irec[j];
    float4 q = qrec[j];
    size_t m = (size_t)(g * NS + j) * 3;
    qpos[m + 0] = q.x; qpos[m + 1] = q.y; qpos[m + 2] = q.z;
  }
}

// ---- radius: 4 lanes/sample stripe scan + mapset; XCD-pinned (graph = blk&7) ----
__global__ __launch_bounds__(256, 1) void radius_kernel(
    const float* __restrict__ pos, const float* __restrict__ qpos,
    int* __restrict__ cols, int* __restrict__ cnt,
    const int* __restrict__ idxf, int* __restrict__ mp) {
  __shared__ float spx[NPG], spy[NPG], spz[NPG];
  __shared__ int sbuf[KN][64][4];
  const int g = blockIdx.x & 7;
  const int s0 = (blockIdx.x >> 3) * 64;
  const float* pgc = pos + (size_t)g * NPG * 3;
  for (int i = threadIdx.x; i < NPG * 3; i += 256) {
    float v = pgc[i]; int node = i / 3, cc = i - node * 3;
    if (cc == 0) spx[node] = v; else if (cc == 1) spy[node] = v; else spz[node] = v;
  }
  __syncthreads();
  const int group = threadIdx.x >> 2;
  const int j = threadIdx.x & 3;
  const int m = g * NS + s0 + group;
  if (j == 0) mp[idxf[m]] = m;
  const float qx = qpos[(size_t)m * 3], qy = qpos[(size_t)m * 3 + 1],
              qz = qpos[(size_t)m * 3 + 2];
  int c = 0;
  const int i0 = j * 1024;
  for (int i = i0; i < i0 + 1024; ++i) {
    float dx = __fsub_rn(spx[i], qx);
    float dy = __fsub_rn(spy[i], qy);
    float dz = __fsub_rn(spz[i], qz);
    float d2 = __fadd_rn(__fadd_rn(__fmul_rn(dx, dx), __fmul_rn(dy, dy)), __fmul_rn(dz, dz));
    if (d2 < 0.16f) {
      sbuf[c][group][j] = i;
      if (++c == KN) break;
    }
  }
  const int lbase = (threadIdx.x & 63) & ~3;
  int c0 = __shfl(c, lbase + 0), c1 = __shfl(c, lbase + 1),
      c2 = __shfl(c, lbase + 2), c3 = __shfl(c, lbase + 3);
  int pre = (j > 0 ? c0 : 0) + (j > 1 ? c1 : 0) + (j > 2 ? c2 : 0);
  int total = c0 + c1 + c2 + c3;
  if (j == 0) cnt[m] = total < KN ? total : KN;
  int take = KN - pre;
  take = take < 0 ? 0 : (take > c ? c : take);
  int* outp = cols + (size_t)m * KN + pre;
  for (int i = 0; i < take; ++i) outp[i] = sbuf[i][group][j];
}

// ---- PointConv: 4 samples/block, XCD-pinned so h2[graph] (2MB) is L2-local ----
__global__ __launch_bounds__(256) void pointconv_kernel(const float* __restrict__ h2,
                                                        const float* __restrict__ pos,
                                                        const float* __restrict__ qpos,
                                                        const int* __restrict__ cols,
                                                        const int* __restrict__ cnt,
                                                        float* __restrict__ xint) {
  const int g = blockIdx.x & 7;
  const int chunk = blockIdx.x >> 3;
  const int ss = threadIdx.x >> 6;
  const int t = threadIdx.x & 63;
  const int m = g * NS + chunk * 4 + ss;
  int n = cnt[m];
  const int* cl = cols + (size_t)m * KN;
  float m0 = -INFINITY, m1 = -INFINITY, mp = -INFINITY;
  for (int k = 0; k < n; ++k) {
    int c = cl[k];
    size_t base = (size_t)(g * NPG + c);
    m0 = fmaxf(m0, h2[base * 128 + t]);
    m1 = fmaxf(m1, h2[base * 128 + 64 + t]);
    if (t < 3) mp = fmaxf(mp, pos[base * 3 + t]);
  }
  float* xo = xint + (size_t)m * 131;
  xo[t] = m0;
  xo[64 + t] = m1;
  if (t < 3) xo[128 + t] = __fsub_rn(mp, qpos[(size_t)m * 3 + t]);
}

// ---- post2: feat3 (SPB samples/block) + deg2 (XCD-pinned edge blocks) ----
__global__ void post2_kernel(const float* __restrict__ xint, const int* __restrict__ idxf,
                             const float* __restrict__ norm, const float* __restrict__ pos,
                             const float* __restrict__ x, const float* __restrict__ W3,
                             float* __restrict__ t3,
                             const int* __restrict__ ei, const int* __restrict__ mp,
                             int* __restrict__ deg) {
  if (blockIdx.x >= NF3B) {
    int wb = blockIdx.x - NF3B;
    int eb = (wb & 7) * 256 + (wb >> 3);
    int e = eb * 256 + threadIdx.x;
    int ns = mp[ei[e]], nd = mp[ei[NE + e]];
    if (ns >= 0 && nd >= 0) atomicAdd(&deg[nd], 1);
    return;
  }
  __shared__ float srow[SPB][140];
  const int m0 = blockIdx.x * SPB;
  for (int jj = threadIdx.x; jj < SPB * 139; jj += 256) {
    int sub = jj / 139, i = jj - sub * 139;
    int m = m0 + sub;
    srow[sub][i] = (i < 131) ? xint[(size_t)m * 131 + i]
                             : inp_val(norm, pos, x, idxf[m], i - 131);
  }
  __syncthreads();
  int f = threadIdx.x;
  float acc[SPB];
#pragma unroll
  for (int s = 0; s < SPB; ++s) acc[s] = 0.f;
#pragma unroll 4
  for (int i = 0; i < 139; ++i) {
    float wv = W3[i * 256 + f];
#pragma unroll
    for (int s = 0; s < SPB; ++s) acc[s] += srow[s][i] * wv;
  }
#pragma unroll
  for (int s = 0; s < SPB; ++s) t3[(size_t)(m0 + s) * 256 + f] = acc[s];
}

__global__ void fill2_kernel(const int* __restrict__ ei, const int* __restrict__ mp,
                             const int* __restrict__ off, int* __restrict__ cur,
                             int* __restrict__ el) {
  int b = blockIdx.x;
  int eb = (b & 7) * 256 + (b >> 3);
  int e = eb * 256 + threadIdx.x;
  int ns = mp[ei[e]], nd = mp[ei[NE + e]];
  if (ns >= 0 && nd >= 0) {
    int p = off[nd] + atomicAdd(&cur[nd], 1);
    el[p] = ns;
  }
}

// single-block exclusive scan, n <= 32768, writes out[0..n]
__global__ __launch_bounds__(1024) void scan_kernel(const int* __restrict__ in,
                                                    int* __restrict__ out, int n) {
  __shared__ int ls[1024];
  int tid = threadIdx.x;
  int per = (n + 1023) >> 10;
  int base = tid * per;
  int s = 0;
  for (int i = 0; i < per; ++i) { int idx = base + i; if (idx < n) s += in[idx]; }
  ls[tid] = s;
  __syncthreads();
  for (int d = 1; d < 1024; d <<= 1) {
    int v = (tid >= d) ? ls[tid - d] : 0;
    __syncthreads();
    ls[tid] += v;
    __syncthreads();
  }
  int excl = (tid == 0) ? 0 : ls[tid - 1];
  for (int i = 0; i < per; ++i) {
    int idx = base + i;
    if (idx < n) { out[idx] = excl; excl += in[idx]; }
  }
  if (tid == 1023) out[n] = ls[1023];
}

// ---- agg3 + pool fused, XCD-pinned so t3[graph] (2MB) is L2-local ----
__global__ void aggpool_kernel(const float* __restrict__ t, const int* __restrict__ off,
                               const int* __restrict__ el, const float* __restrict__ b,
                               float* __restrict__ pooled) {
  int node = (blockIdx.x & 7) * 2048 + (blockIdx.x >> 3);
  int f = threadIdx.x;
  int e0 = off[node], e1 = off[node + 1];
  float acc = 0.f;
  for (int j = e0; j < e1; ++j) acc += t[(size_t)el[j] * 256 + f];
  float val = fmaxf(acc + b[f], 0.f);
  atomicMax((int*)pooled + (node >> 11) * 256 + f, __float_as_int(val));
}

__global__ void head_kernel(const float* __restrict__ pooled, const float* __restrict__ lw,
                            const float* __restrict__ lb, float* __restrict__ outp) {
  __shared__ float lg[NG * NC];
  int t = threadIdx.x;
  if (t < NG * NC) {
    int g = t / NC, c = t % NC;
    float acc = lb[c];
    for (int k = 0; k < 256; ++k) acc += pooled[g * 256 + k] * lw[k * NC + c];
    lg[t] = acc;
  }
  __syncthreads();
  if (t < NG) {
    int g = t;
    float mx = -INFINITY;
    for (int c = 0; c < NC; ++c) mx = fmaxf(mx, lg[g * NC + c]);
    float sum = 0.f;
    for (int c = 0; c < NC; ++c) sum += expf(lg[g * NC + c] - mx);
    float lse = logf(sum);
    float ov[NC];
    float mx2 = -INFINITY;
    for (int c = 0; c < NC; ++c) {
      ov[c] = lg[g * NC + c] - mx - lse;
      outp[g * NC + c] = ov[c];
      mx2 = fmaxf(mx2, ov[c]);
    }
    float s2 = 0.f;
    for (int c = 0; c < NC; ++c) s2 += expf(ov[c] - mx2);
    for (int c = 0; c < NC; ++c) outp[NG * NC + g * NC + c] = expf(ov[c] - mx2) / s2;
  }
}

extern "C" void kernel_launch(void* const* d_in, const int* in_sizes, int n_in,
                              void* d_out, int out_size, void* d_ws, size_t ws_size,
                              hipStream_t stream) {
  const float* norm = (const float*)d_in[0];
  const float* pos  = (const float*)d_in[1];
  const float* x    = (const float*)d_in[2];
  const int* ei     = (const int*)d_in[3];   // int32! row0 = src, row1 = dst
  const float* W1 = (const float*)d_in[5];
  const float* b1 = (const float*)d_in[6];
  const float* W2 = (const float*)d_in[7];
  const float* b2 = (const float*)d_in[8];
  const float* W3 = (const float*)d_in[9];
  const float* b3 = (const float*)d_in[10];
  const float* lw = (const float*)d_in[11];
  const float* lb = (const float*)d_in[12];
  float* outp = (float*)d_out;

  char* w = (char*)d_ws;
  size_t o = 0;
  auto alloc = [&](size_t bytes) -> void* {
    void* p = w + o;
    o = (o + bytes + 255) & ~(size_t)255;
    return p;
  };
  // zero-group (single memset): deg1,cur1,deg2,cur2,pooled,wctr contiguous
  int* deg1   = (int*)alloc((size_t)NT * 4);
  int* cur1   = (int*)alloc((size_t)NT * 4);
  int* deg2   = (int*)alloc((size_t)GS * 4);
  int* cur2   = (int*)alloc((size_t)GS * 4);
  float* pooled = (float*)alloc((size_t)NG * 256 * 4);
  int* wctr   = (int*)alloc(128);
  size_t zlen = o;
  float* A    = (float*)alloc((size_t)NT * 128 * 4);  // t2 -> t3
  float* Bf   = (float*)alloc((size_t)NT * 128 * 4);  // h2
  float* T1   = (float*)alloc((size_t)NT * 64 * 4);   // t1
  float* xint = (float*)alloc((size_t)GS * 131 * 4);
  int* cols   = (int*)alloc((size_t)GS * KN * 4);
  int* cnt    = (int*)alloc((size_t)GS * 4);
  int* off1   = (int*)alloc((size_t)(NT + 1) * 4);
  int* el1    = (int*)alloc((size_t)NE * 4);
  int* off2   = (int*)alloc((size_t)(GS + 1) * 4);
  int* el2    = (int*)alloc((size_t)NE * 4);
  int* idxf   = (int*)alloc((size_t)GS * 4);
  float* qpos = (float*)alloc((size_t)GS * 3 * 4);
  int* mapv   = (int*)alloc((size_t)NT * 4);

  hipMemsetAsync(w, 0, zlen, stream);
  hipMemsetAsync(mapv, 0xFF, (size_t)NT * 4, stream);  // -1

  // phase A (cooperative): fps ∥ {GCN layers 1-2}; workers exit early
  {
    void* ka[] = {(void*)&pos, (void*)&idxf, (void*)&qpos, (void*)&norm, (void*)&x,
                  (void*)&W1, (void*)&T1, (void*)&ei, (void*)&deg1,
                  (void*)&off1, (void*)&cur1, (void*)&el1,
                  (void*)&b1, (void*)&W2, (void*)&A, (void*)&b2, (void*)&Bf,
                  (void*)&wctr};
    hipLaunchCooperativeKernel((const void*)phaseA_kernel, dim3(8 + NWORK), dim3(256),
                               ka, 0, stream);
  }
  // tail: all gather stages XCD-pinned per graph
  radius_kernel<<<256, 256, 0, stream>>>(pos, qpos, cols, cnt, idxf, mapv);
  pointconv_kernel<<<GS / 4, 256, 0, stream>>>(Bf, pos, qpos, cols, cnt, xint);
  post2_kernel<<<NF3B + 2048, 256, 0, stream>>>(xint, idxf, norm, pos, x, W3, A,
                                                ei, mapv, deg2);
  scan_kernel<<<1, 1024, 0, stream>>>(deg2, off2, GS);
  fill2_kernel<<<2048, 256, 0, stream>>>(ei, mapv, off2, cur2, el2);
  aggpool_kernel<<<GS, 256, 0, stream>>>(A, off2, el2, b3, pooled);
  head_kernel<<<1, 128, 0, stream>>>(pooled, lw, lb, outp);
}